// Round 7
// baseline (72.150 us; speedup 1.0000x reference)
//
#include <hip/hip_runtime.h>

// ContrastiveLoss on MI355X — fully fused: one prep kernel + one persistent
// main kernel (gram + neg reduction + pos compare + finalize).
// Shapes fixed by reference: K=8 groups, BS=256, F=512, N=4096. 128-row
// tiles are class-uniform; upper triangle = 528 tiles always (nn neg + np pos).
//
// Fusion correctness:
//  - each of 528 blocks atomically pops ONE job (neg-first list) -> all nn
//    (<=496) neg jobs are held by co-resident blocks (512 slots at 2/CU),
//    so pos blocks spinning on negDone cannot deadlock, regardless of
//    dispatch order.
//  - pos blocks keep acc in REGISTERS while spinning (no dots round-trip).
//  - all cross-block reads after the spin use device-scope atomic loads
//    (no kernel boundary to invalidate L1s anymore).
// Gram body = round-5's best-measured: shared staging, 4-buffer LDS,
// 3-ahead, counted vmcnt(8), XOR chunk swizzle (both-sides, rule #21).

#define KGRP 8
#define FD   512
#define N1T  2048
#define NT   4096
#define TEMPW 0.02f

typedef __attribute__((ext_vector_type(8))) short short8;
typedef __attribute__((ext_vector_type(4))) float f32x4;
typedef unsigned short ushort_t;

// ---- helpers ---------------------------------------------------------------

__device__ __forceinline__ unsigned enc_ord(float f) {
  unsigned u = __float_as_uint(f);
  return (u & 0x80000000u) ? ~u : (u | 0x80000000u);
}
__device__ __forceinline__ float dec_ord(unsigned u) {
  unsigned b = (u & 0x80000000u) ? (u & 0x7fffffffu) : ~u;
  return __uint_as_float(b);
}

__device__ __forceinline__ ushort_t f2bf(float f) {
  unsigned u = __float_as_uint(f);
  u = (u + 0x7fffu + ((u >> 16) & 1u)) >> 16;
  return (ushort_t)u;
}

__device__ __forceinline__ void gld16(const void* g, void* l) {
  __builtin_amdgcn_global_load_lds(
      (const __attribute__((address_space(1))) unsigned*)g,
      (__attribute__((address_space(3))) unsigned*)l, 16, 0, 0);
}

// cnts layout: [0]=nn [1]=np [2]=job pop counter [3]=negDone [4]=posDone

// ---- prep: bf16 convert + zero accumulators + class table + tile lists -----
__global__ __launch_bounds__(256) void prep_k(
    const float* __restrict__ f1, const float* __restrict__ f2,
    ushort_t* __restrict__ bf,
    float* __restrict__ neg_sum, unsigned* __restrict__ neg_max,
    float* __restrict__ sumS, float* __restrict__ corr,
    int* __restrict__ cnts, int* __restrict__ neg_list,
    int* __restrict__ pos_list, const int* __restrict__ ov)
{
  const int b = blockIdx.x, t = threadIdx.x;

  {
    int i = b * 256 + t;
    size_t base = (size_t)i * 8;
    const size_t half = (size_t)N1T * FD;
    const float* sp = (base < half) ? (f1 + base) : (f2 + (base - half));
    float4 u0 = ((const float4*)sp)[0];
    float4 u1 = ((const float4*)sp)[1];
    short8 o;
    o[0] = (short)f2bf(u0.x); o[1] = (short)f2bf(u0.y);
    o[2] = (short)f2bf(u0.z); o[3] = (short)f2bf(u0.w);
    o[4] = (short)f2bf(u1.x); o[5] = (short)f2bf(u1.y);
    o[6] = (short)f2bf(u1.z); o[7] = (short)f2bf(u1.w);
    *(short8*)(bf + base) = o;
  }

  if (b >= 1 && b <= 16) {
    int i = (b - 1) * 256 + t;
    neg_sum[i] = 0.f;
    neg_max[i] = 0u;                    // 0u < enc_ord(any float)
  }

  if (b == 0) {
    __shared__ int c[16];
    if (t == 0) {
      sumS[0] = 0.f; corr[0] = 0.f;
      cnts[0] = 0; cnts[1] = 0; cnts[2] = 0; cnts[3] = 0; cnts[4] = 0;
      int excl = 0;
      for (int g = 0; g < KGRP; g++) c[g] = g;
      for (int g = 0; g < KGRP; g++) {
        if (ov[g]) c[KGRP + g] = g;
        else       { c[KGRP + g] = KGRP + excl; excl++; }
      }
    }
    __syncthreads();
    for (int p = t; p < 1024; p += 256) {
      int bi = p >> 5, bj = p & 31;
      if (bj < bi) continue;
      if (c[bi >> 1] == c[bj >> 1]) {
        int k = atomicAdd(&cnts[1], 1); pos_list[k] = (bi << 5) | bj;
      } else {
        int k = atomicAdd(&cnts[0], 1); neg_list[k] = (bi << 5) | bj;
      }
    }
  }
}

// ---- persistent fused main kernel ------------------------------------------
__global__ __launch_bounds__(256, 2) void main_k(
    const ushort_t* __restrict__ bf, int* __restrict__ cnts,
    const int* __restrict__ neg_list, const int* __restrict__ pos_list,
    float* __restrict__ neg_sum, unsigned* __restrict__ neg_max,
    float* __restrict__ sumS, float* __restrict__ corr,
    const int* __restrict__ ov, float* __restrict__ out)
{
  __shared__ char lds[4 * 16384];      // gram staging; reused post-gram
  __shared__ int jid_sh;
  __shared__ int amLast;

  const int t = threadIdx.x;
  if (t == 0) jid_sh = atomicAdd(&cnts[2], 1);   // pop one job
  __syncthreads();
  const int k  = jid_sh;
  const int nn = cnts[0], np = cnts[1];
  const bool isneg = (k < nn);
  const int pr = isneg ? neg_list[k] : pos_list[k - nn];
  const int bi = pr >> 5, bj = pr & 31;
  const int brow = bi << 7, bcol = bj << 7;

  const int lane = t & 63, wave = t >> 6;
  const int wrow = (wave >> 1) << 6, wcol = (wave & 1) << 6;
  const int fr   = lane & 15, fh = lane >> 4;

  // ---- gram (r5 body): shared staging, 4 bufs, 3-ahead, vmcnt(8) ----
  const int r_in = t >> 2;
  const int csw  = (((t & 3) ^ ((t >> 3) & 3)) << 3);
  const ushort_t* gA = bf + (size_t)(brow + r_in) * FD + csw;
  const ushort_t* gB = bf + (size_t)(bcol + r_in) * FD + csw;
  const int ldsw = wave << 10;

  const int fx = ((fh ^ ((fr >> 1) & 3)) << 4);
  int offA[4], offB[4];
#pragma unroll
  for (int m = 0; m < 4; m++) offA[m] = ((wrow + (m << 4) + fr) << 6) + fx;
#pragma unroll
  for (int n = 0; n < 4; n++) offB[n] = 8192 + ((wcol + (n << 4) + fr) << 6) + fx;

  f32x4 acc[4][4];
#pragma unroll
  for (int m = 0; m < 4; m++)
#pragma unroll
    for (int n = 0; n < 4; n++)
      acc[m][n] = (f32x4){0.f, 0.f, 0.f, 0.f};

  auto stage = [&](int s) {
    char* dst = lds + ((s & 3) * 16384) + ldsw;
    const ushort_t* a = gA + (s << 5);
    const ushort_t* p = gB + (s << 5);
    gld16(a,                   dst);
    gld16(a + (size_t)64 * FD, dst + 4096);
    gld16(p,                   dst + 8192);
    gld16(p + (size_t)64 * FD, dst + 12288);
  };

  stage(0); stage(1); stage(2);

#pragma unroll
  for (int s = 0; s < 16; s++) {
    if (s < 14)       asm volatile("s_waitcnt vmcnt(8)" ::: "memory");
    else if (s == 14) asm volatile("s_waitcnt vmcnt(4)" ::: "memory");
    else              asm volatile("s_waitcnt vmcnt(0)" ::: "memory");
    __builtin_amdgcn_s_barrier();
    asm volatile("" ::: "memory");

    char* base = lds + (s & 3) * 16384;
    short8 a[4], bb[4];
#pragma unroll
    for (int m = 0; m < 4; m++) a[m]  = *(const short8*)(base + offA[m]);
#pragma unroll
    for (int n = 0; n < 4; n++) bb[n] = *(const short8*)(base + offB[n]);

    if (s + 3 < 16) stage(s + 3);

#pragma unroll
    for (int m = 0; m < 4; m++)
#pragma unroll
      for (int n = 0; n < 4; n++)
        acc[m][n] = __builtin_amdgcn_mfma_f32_16x16x32_bf16(a[m], bb[n], acc[m][n], 0, 0, 0);
  }

  const int rbase = brow + wrow + (fh << 2);
  const int cbase = bcol + wcol + fr;

  if (isneg) {
    // ---- neg epilogue: row + col exp-sums/maxes, one exp per dot ----
    float colS[4] = {0.f, 0.f, 0.f, 0.f};
    float colM[4] = {-3.0e38f, -3.0e38f, -3.0e38f, -3.0e38f};
#pragma unroll
    for (int m = 0; m < 4; m++) {
#pragma unroll
      for (int j = 0; j < 4; j++) {
        float s = 0.f, mx = -3.0e38f;
#pragma unroll
        for (int n = 0; n < 4; n++) {
          float d = acc[m][n][j];
          float e = __expf(d * TEMPW);
          s += e; mx = fmaxf(mx, d);
          colS[n] += e; colM[n] = fmaxf(colM[n], d);
        }
#pragma unroll
        for (int o = 1; o < 16; o <<= 1) {
          s  += __shfl_xor(s, o, 64);
          mx  = fmaxf(mx, __shfl_xor(mx, o, 64));
        }
        if (fr == 0) {
          int r = rbase + (m << 4) + j;
          atomicAdd(&neg_sum[r], s);
          atomicMax(&neg_max[r], enc_ord(mx));
        }
      }
    }
#pragma unroll
    for (int n = 0; n < 4; n++) {
      float s = colS[n], mx = colM[n];
      s += __shfl_xor(s, 16, 64); mx = fmaxf(mx, __shfl_xor(mx, 16, 64));
      s += __shfl_xor(s, 32, 64); mx = fmaxf(mx, __shfl_xor(mx, 32, 64));
      if (fh == 0) {
        int c = cbase + (n << 4);
        atomicAdd(&neg_sum[c], s);
        atomicMax(&neg_max[c], enc_ord(mx));
      }
    }
    __syncthreads();                    // drain all this block's atomics
    if (t == 0) { __threadfence(); atomicAdd(&cnts[3], 1); }
    return;
  }

  // ---- pos path: acc stays in registers; wait for all neg blocks ----
  if (t == 0) {
    while (atomicAdd(&cnts[3], 0) < nn) __builtin_amdgcn_s_sleep(8);
  }
  __syncthreads();

  // stage final neg_max (rows + cols of this tile) into LDS via atomic reads
  float* nmf = (float*)lds;             // [0..127]=rows, [128..255]=cols
  if (t < 128) nmf[t] = dec_ord(atomicAdd(&neg_max[brow + t], 0u));
  else         nmf[t] = dec_ord(atomicAdd(&neg_max[bcol + (t - 128)], 0u));
  __syncthreads();

  const float cw = ((bi < 16) == (bj < 16)) ? 1.0f : 0.5f;
  float ssum = 0.f;
  int cc = 0;
  if (bi == bj) {
#pragma unroll
    for (int m = 0; m < 4; m++)
#pragma unroll
      for (int j = 0; j < 4; j++) {
        int rloc = wrow + (fh << 2) + (m << 4) + j;
        float nmr = nmf[rloc];
#pragma unroll
        for (int n = 0; n < 4; n++) {
          int cloc = wcol + fr + (n << 4);
          if (rloc != cloc) {           // exclude diagonal
            float d = acc[m][n][j];
            ssum += d;
            cc += (d > nmr) ? 1 : 0;
          }
        }
      }
  } else {
    float nmc[4];
#pragma unroll
    for (int n = 0; n < 4; n++) nmc[n] = nmf[128 + wcol + fr + (n << 4)];
#pragma unroll
    for (int m = 0; m < 4; m++)
#pragma unroll
      for (int j = 0; j < 4; j++) {
        float nmr = nmf[wrow + (fh << 2) + (m << 4) + j];
#pragma unroll
        for (int n = 0; n < 4; n++) {
          float d = acc[m][n][j];
          ssum += d;
          cc += ((d > nmr) ? 1 : 0) + ((d > nmc[n]) ? 1 : 0);
        }
      }
    ssum *= 2.0f;                       // both orientations
  }
  ssum *= cw;

#pragma unroll
  for (int o = 1; o < 64; o <<= 1) {
    ssum += __shfl_xor(ssum, o, 64);
    cc   += __shfl_xor(cc, o, 64);
  }
  __syncthreads();                      // nmf no longer needed; reuse lds
  float* wsum = (float*)(lds);
  int*   wcnt = (int*)(lds + 64);
  if (lane == 0) { wsum[wave] = ssum; wcnt[wave] = cc; }
  __syncthreads();
  if (t == 0) {
    float S2 = 0.f; int C2 = 0;
    for (int w = 0; w < 4; w++) { S2 += wsum[w]; C2 += wcnt[w]; }
    atomicAdd(sumS, S2);
    atomicAdd(corr, (float)C2);
    __threadfence();
    int my = atomicAdd(&cnts[4], 1);
    amLast = (my == np - 1) ? 1 : 0;
  }
  __syncthreads();
  if (!amLast) return;

  // ---- finalize (runs in exactly one block, after all pos blocks) ----
  float aa = 0.f;
  for (int r = t; r < NT; r += 256) {
    int g = r >> 8;                     // 256-row group, 0..15
    float W = ov[g & 7] ? 383.f : 255.f;
    float ns = atomicAdd(&neg_sum[r], 0.f);   // device-coherent read
    aa += W * __logf(ns);
  }
#pragma unroll
  for (int o = 1; o < 64; o <<= 1) aa += __shfl_xor(aa, o, 64);
  if (lane == 0) wsum[wave] = aa;
  __syncthreads();
  if (t == 0) {
    float sw = wsum[0] + wsum[1] + wsum[2] + wsum[3];
    float S = atomicAdd(sumS, 0.f);
    float C = atomicAdd(corr, 0.f);
    float tp = 0.f;
    for (int g = 0; g < 16; g++) tp += 256.f * (255.f + 256.f * (ov[g & 7] ? 1.f : 0.f));
    out[0] = C / tp;
    out[1] = (sw - TEMPW * S) / tp;
  }
}

// ---- launch ----------------------------------------------------------------

extern "C" void kernel_launch(void* const* d_in, const int* in_sizes, int n_in,
                              void* d_out, int out_size, void* d_ws, size_t ws_size,
                              hipStream_t stream)
{
  const float* f1 = (const float*)d_in[0];
  const float* f2 = (const float*)d_in[1];
  const int*   ov = (const int*)d_in[2];

  char* ws = (char*)d_ws;
  ushort_t* bf       = (ushort_t*)ws;                                    // 4 MB
  float*    neg_sum  = (float*)(ws + (size_t)(4 << 20));                 // 16 KB
  unsigned* neg_max  = (unsigned*)(ws + (size_t)(4 << 20) + (16 << 10)); // 16 KB
  float*    sumS     = (float*)(ws + (size_t)(4 << 20) + (32 << 10));
  float*    corr     = sumS + 1;
  int*      cnts     = (int*)(sumS + 2);                                 // 5 ints
  int*      neg_list = (int*)(ws + (size_t)(4 << 20) + (36 << 10));      // <=496
  int*      pos_list = (int*)(ws + (size_t)(4 << 20) + (40 << 10));      // <=80
  float*    out      = (float*)d_out;

  hipLaunchKernelGGL(prep_k, dim3(1024), dim3(256), 0, stream,
                     f1, f2, bf, neg_sum, neg_max, sumS, corr, cnts,
                     neg_list, pos_list, ov);
  hipLaunchKernelGGL(main_k, dim3(528), dim3(256), 0, stream,
                     bf, cnts, neg_list, pos_list, neg_sum, neg_max,
                     sumS, corr, ov, out);
}